// Round 1
// baseline (628.406 us; speedup 1.0000x reference)
//
#include <hip/hip_runtime.h>
#include <hip/hip_bf16.h>
#include <stdint.h>

// MLAAttention on MI355X (gfx950).
// B=4 T=4096 D=1024 H=16 M=64 Dh=64. All inputs f32 (mask int32), output f32.
// Pipeline: cvt->bf16 | 3x GEMM(x,W^T) | rope(q,k) | stage1 online colmax/colsum
//           | P^T materialization (bf16) | latgemm (P^T @ [K|V]) | stage2 fused attn
//           | GEMM(attn, Wo^T) -> f32 out.

#define DEV static __device__ __forceinline__

using short8 = __attribute__((ext_vector_type(8))) short;
using f32x4  = __attribute__((ext_vector_type(4))) float;

#define ZERO4 (f32x4){0.f, 0.f, 0.f, 0.f}

DEV float bf2f(unsigned short u) {
  union { unsigned int i; float f; } c; c.i = ((unsigned int)u) << 16; return c.f;
}
DEV unsigned short f2bf(float f) {
  __hip_bfloat16 h = __float2bfloat16(f);
  unsigned short u; __builtin_memcpy(&u, &h, 2); return u;
}
DEV f32x4 mfma16(short8 a, short8 b, f32x4 c) {
  return __builtin_amdgcn_mfma_f32_16x16x32_bf16(a, b, c, 0, 0, 0);
}
#define GLOAD_LDS16(G, L) __builtin_amdgcn_global_load_lds( \
    (const __attribute__((address_space(1))) void*)(G),     \
    (__attribute__((address_space(3))) void*)(L), 16, 0, 0)

// ---------------------------------------------------------------- convert
__global__ void cvt_bf16(const float* __restrict__ src,
                         __hip_bfloat16* __restrict__ dst, int n) {
  int i = (blockIdx.x * blockDim.x + threadIdx.x) * 4;
  if (i >= n) return;
  const float4 v = *(const float4*)(src + i);
  ushort4 o;
  o.x = f2bf(v.x); o.y = f2bf(v.y); o.z = f2bf(v.z); o.w = f2bf(v.w);
  *(ushort4*)(dst + i) = o;
}

// ---------------------------------------------------------------- GEMM 128x128
// C[M,N] = A[M,K] @ Bt[N,K]^T, bf16 in, f32 acc. m97 structure.
template<int STORE_BF16>
__global__ __launch_bounds__(256)
void gemm128(const __hip_bfloat16* __restrict__ A,
             const __hip_bfloat16* __restrict__ Bt,
             void* __restrict__ Cout, int M, int N, int K) {
  __shared__ __hip_bfloat16 As[128 * 64];
  __shared__ __hip_bfloat16 Bs[128 * 64];
  const int tid = threadIdx.x;
  const int w = tid >> 6, l = tid & 63;
  const int rowA0 = blockIdx.x * 128;
  const int colB0 = blockIdx.y * 128;
  const int srow = w * 8 + (l >> 3);      // staging row within 32-row group
  const int skk  = (l & 7) * 8;           // staging k offset (8 bf16 = 16B)
  const __hip_bfloat16* Ab = A  + (size_t)(rowA0 + srow) * K + skk;
  const __hip_bfloat16* Bb = Bt + (size_t)(colB0 + srow) * K + skk;
  f32x4 acc[4][4];
#pragma unroll
  for (int i = 0; i < 4; ++i)
#pragma unroll
    for (int j = 0; j < 4; ++j) acc[i][j] = ZERO4;
  const int wr = (w >> 1) * 64, wc = (w & 1) * 64;
  for (int k0 = 0; k0 < K; k0 += 64) {
    __syncthreads();
#pragma unroll
    for (int i = 0; i < 4; ++i) {
      GLOAD_LDS16(Ab + (size_t)(i * 32) * K + k0, &As[i * 2048 + w * 512]);
      GLOAD_LDS16(Bb + (size_t)(i * 32) * K + k0, &Bs[i * 2048 + w * 512]);
    }
    __syncthreads();
#pragma unroll
    for (int s = 0; s < 2; ++s) {
      short8 fa[4], fb[4];
#pragma unroll
      for (int i = 0; i < 4; ++i)
        fa[i] = *(const short8*)&As[(wr + i * 16 + (l & 15)) * 64 + s * 32 + (l >> 4) * 8];
#pragma unroll
      for (int j = 0; j < 4; ++j)
        fb[j] = *(const short8*)&Bs[(wc + j * 16 + (l & 15)) * 64 + s * 32 + (l >> 4) * 8];
#pragma unroll
      for (int i = 0; i < 4; ++i)
#pragma unroll
        for (int j = 0; j < 4; ++j)
          acc[i][j] = mfma16(fa[i], fb[j], acc[i][j]);
    }
  }
  const int r0 = rowA0 + wr + (l >> 4) * 4;
  const int c0 = colB0 + wc + (l & 15);
#pragma unroll
  for (int i = 0; i < 4; ++i)
#pragma unroll
    for (int j = 0; j < 4; ++j)
#pragma unroll
      for (int r = 0; r < 4; ++r) {
        const size_t idx = (size_t)(r0 + i * 16 + r) * N + (c0 + j * 16);
        if (STORE_BF16) ((__hip_bfloat16*)Cout)[idx] = __float2bfloat16(acc[i][j][r]);
        else            ((float*)Cout)[idx]          = acc[i][j][r];
      }
}

// ---------------------------------------------------------------- RoPE in-place
// qk: packed bf16 pairs [B*T, H, 32] (one dword = one rotation pair)
__global__ void rope_inplace(unsigned int* __restrict__ qk,
                             const float* __restrict__ cosT,
                             const float* __restrict__ sinT) {
  const int i = blockIdx.x * 256 + threadIdx.x;   // 8388608 pairs
  const int tpos = (i >> 9) & 4095;               // 512 pairs per token row
  const int dh = (i & 31) * 2;                    // pair index within head * 2
  const unsigned int v = qk[i];
  const float x0 = bf2f((unsigned short)(v & 0xffffu));
  const float x1 = bf2f((unsigned short)(v >> 16));
  const float c = cosT[tpos * 64 + dh];
  const float s = sinT[tpos * 64 + dh];
  const unsigned int lo = f2bf(x0 * c - x1 * s);
  const unsigned int hi = f2bf(x1 * c + x0 * s);
  qk[i] = lo | (hi << 16);
}

// ---------------------------------------------------------------- stage1 stats
// Online (max,sum) over tokens for each (b,h,m); grid (bh, chunk of 512 t).
__global__ __launch_bounds__(256)
void stage1_stats(const __hip_bfloat16* __restrict__ kmat,  // [B,T,H,64] (roped)
                  const float* __restrict__ latent,          // [H,64,64]
                  const int* __restrict__ mask,              // [B*T]
                  float* __restrict__ pmax, float* __restrict__ psum) {
  __shared__ __hip_bfloat16 kt[64][64];
  __shared__ float rmx[256], rsm[256];
  const int bh = blockIdx.x, chunk = blockIdx.y;
  const int b = bh >> 4, h = bh & 15;
  const int tid = threadIdx.x, m = tid & 63, g = tid >> 6;
  float latr[64];
#pragma unroll
  for (int d4 = 0; d4 < 16; ++d4) {
    const float4 v = *(const float4*)&latent[((size_t)(h * 64 + m)) * 64 + d4 * 4];
    latr[d4 * 4 + 0] = v.x; latr[d4 * 4 + 1] = v.y;
    latr[d4 * 4 + 2] = v.z; latr[d4 * 4 + 3] = v.w;
  }
  float mx = -3.0e38f, sm = 0.f;
  const int tbase = chunk * 512;
  for (int tt = 0; tt < 512; tt += 64) {
    __syncthreads();
    for (int i = tid; i < 512; i += 256) {
      const int r = i >> 3, o = (i & 7) * 8;
      *(uint4*)&kt[r][o] =
          *(const uint4*)&kmat[((size_t)(b * 4096 + tbase + tt + r) * 16 + h) * 64 + o];
    }
    __syncthreads();
    for (int tl = 0; tl < 16; ++tl) {
      const int t = g * 16 + tl;
      float dot = 0.f;
#pragma unroll
      for (int d8 = 0; d8 < 8; ++d8) {
        const short8 kv = *(const short8*)&kt[t][d8 * 8];
#pragma unroll
        for (int jj = 0; jj < 8; ++jj)
          dot += bf2f((unsigned short)kv[jj]) * latr[d8 * 8 + jj];
      }
      dot *= 0.125f;
      if (mask[b * 4096 + tbase + tt + t] != 0) {
        const float nmx = fmaxf(mx, dot);
        sm = sm * __expf(mx - nmx) + __expf(dot - nmx);
        mx = nmx;
      }
    }
  }
  rmx[tid] = mx; rsm[tid] = sm;
  __syncthreads();
  if (g == 0) {
#pragma unroll
    for (int gg = 1; gg < 4; ++gg) {
      const float omx = rmx[gg * 64 + m], osm = rsm[gg * 64 + m];
      const float nmx = fmaxf(mx, omx);
      sm = sm * __expf(mx - nmx) + osm * __expf(omx - nmx);
      mx = nmx;
    }
    pmax[((size_t)bh * 8 + chunk) * 64 + m] = mx;
    psum[((size_t)bh * 8 + chunk) * 64 + m] = sm;
  }
}

__global__ void stage1_reduce(const float* __restrict__ pmax,
                              const float* __restrict__ psum,
                              float* __restrict__ cmax, float* __restrict__ cinv) {
  const int i = blockIdx.x * 256 + threadIdx.x;
  if (i >= 4096) return;
  const int bh = i >> 6, m = i & 63;
  float mx = -3.0e38f;
#pragma unroll
  for (int c = 0; c < 8; ++c)
    mx = fmaxf(mx, pmax[((size_t)bh * 8 + c) * 64 + m]);
  float sm = 0.f;
#pragma unroll
  for (int c = 0; c < 8; ++c)
    sm += psum[((size_t)bh * 8 + c) * 64 + m] *
          __expf(pmax[((size_t)bh * 8 + c) * 64 + m] - mx);
  cmax[i] = mx;
  cinv[i] = 1.f / sm;
}

// P^T materialization: Pt[bh, m, t] bf16 (coalesced over t = lane)
__global__ __launch_bounds__(256)
void stage1_pvals(const __hip_bfloat16* __restrict__ kmat,
                  const float* __restrict__ latent,
                  const int* __restrict__ mask,
                  const float* __restrict__ cmax, const float* __restrict__ cinv,
                  __hip_bfloat16* __restrict__ Pt) {
  const int bh = blockIdx.x >> 4;
  const int t = (blockIdx.x & 15) * 256 + threadIdx.x;
  const int b = bh >> 4, h = bh & 15;
  float kr[64];
  {
    const __hip_bfloat16* kp = &kmat[((size_t)(b * 4096 + t) * 16 + h) * 64];
#pragma unroll
    for (int d8 = 0; d8 < 8; ++d8) {
      const short8 kv = *(const short8*)&kp[d8 * 8];
#pragma unroll
      for (int jj = 0; jj < 8; ++jj) kr[d8 * 8 + jj] = bf2f((unsigned short)kv[jj]);
    }
  }
  const bool live = (mask[b * 4096 + t] != 0);
  for (int m = 0; m < 64; ++m) {
    const float* lp = &latent[((size_t)h * 64 + m) * 64];
    float dot = 0.f;
#pragma unroll
    for (int dd = 0; dd < 64; ++dd) dot += kr[dd] * lp[dd];
    dot *= 0.125f;
    const float p = live ? __expf(dot - cmax[bh * 64 + m]) * cinv[bh * 64 + m] : 0.f;
    Pt[((size_t)bh * 64 + m) * 4096 + t] = __float2bfloat16(p);
  }
}

// ---------------------------------------------------------------- latent GEMM
// k_lat[m,d] = sum_t Pt[m,t]*K[t,d]; v_latT[d,m] = sum_t Pt[m,t]*V[t,d]. One block/(b,h).
__global__ __launch_bounds__(256)
void latgemm(const __hip_bfloat16* __restrict__ Pt,
             const __hip_bfloat16* __restrict__ kmat,
             const __hip_bfloat16* __restrict__ vmat,
             __hip_bfloat16* __restrict__ k_lat,     // [BH,64,64]  (m,d)
             __hip_bfloat16* __restrict__ v_latT) {  // [BH,64,64]  (d,m)
  __shared__ __hip_bfloat16 Ps[64 * 64];    // [m][t]
  __shared__ __hip_bfloat16 Bs[128 * 64];   // [d][t] transposed; d<64:K, d>=64:V
  const int bh = blockIdx.x;
  const int b = bh >> 4, h = bh & 15;
  const int tid = threadIdx.x, w = tid >> 6, l = tid & 63;
  f32x4 acc[4][2];
#pragma unroll
  for (int i = 0; i < 4; ++i) { acc[i][0] = ZERO4; acc[i][1] = ZERO4; }
  for (int tt = 0; tt < 4096; tt += 64) {
    __syncthreads();
    for (int i = tid; i < 512; i += 256) {
      const int r = i >> 3, o = (i & 7) * 8;
      *(uint4*)&Ps[r * 64 + o] = *(const uint4*)&Pt[((size_t)bh * 64 + r) * 4096 + tt + o];
    }
    for (int i = tid; i < 1024; i += 256) {
      const int tl = (i >> 3) & 63;
      const int o = (i & 7) * 8;
      const int isv = i >> 9;
      const __hip_bfloat16* src =
          (isv ? vmat : kmat) + ((size_t)(b * 4096 + tt + tl) * 16 + h) * 64 + o;
      const short8 val = *(const short8*)src;
#pragma unroll
      for (int jj = 0; jj < 8; ++jj)
        ((unsigned short*)Bs)[(isv * 64 + o + jj) * 64 + tl] = (unsigned short)val[jj];
    }
    __syncthreads();
#pragma unroll
    for (int s = 0; s < 2; ++s) {
      short8 fa[4], fb[2];
#pragma unroll
      for (int i = 0; i < 4; ++i)
        fa[i] = *(const short8*)&Ps[(i * 16 + (l & 15)) * 64 + s * 32 + (l >> 4) * 8];
#pragma unroll
      for (int j = 0; j < 2; ++j)
        fb[j] = *(const short8*)&Bs[(w * 32 + j * 16 + (l & 15)) * 64 + s * 32 + (l >> 4) * 8];
#pragma unroll
      for (int i = 0; i < 4; ++i)
#pragma unroll
        for (int j = 0; j < 2; ++j)
          acc[i][j] = mfma16(fa[i], fb[j], acc[i][j]);
    }
  }
#pragma unroll
  for (int i = 0; i < 4; ++i)
#pragma unroll
    for (int j = 0; j < 2; ++j) {
      const int dcol = w * 32 + j * 16 + (l & 15);
#pragma unroll
      for (int r = 0; r < 4; ++r) {
        const int mrow = i * 16 + (l >> 4) * 4 + r;
        const __hip_bfloat16 val = __float2bfloat16(acc[i][j][r]);
        if (dcol < 64) k_lat[((size_t)bh * 64 + mrow) * 64 + dcol] = val;
        else           v_latT[((size_t)bh * 64 + (dcol - 64)) * 64 + mrow] = val;
      }
    }
}

// ---------------------------------------------------------------- stage2 fused
// per block: 64 q-rows of one (b,h). QK_lat^T -> softmax(m) -> @v_lat -> attn(bf16)
__global__ __launch_bounds__(256)
void stage2_attn(const __hip_bfloat16* __restrict__ q,
                 const __hip_bfloat16* __restrict__ k_lat,
                 const __hip_bfloat16* __restrict__ v_latT,
                 __hip_bfloat16* __restrict__ attn) {
  __shared__ unsigned short Pl[4][16][64];   // per-wave P tile, XOR-swizzled
  const int bid = blockIdx.x;
  const int bh = bid >> 6, tt = (bid & 63) * 64;
  const int b = bh >> 4, h = bh & 15;
  const int tid = threadIdx.x, w = tid >> 6, l = tid & 63;
  const size_t qoff = ((size_t)(b * 4096 + tt + w * 16 + (l & 15)) * 16 + h) * 64;
  const short8 a0 = *(const short8*)&q[qoff + (l >> 4) * 8];
  const short8 a1 = *(const short8*)&q[qoff + 32 + (l >> 4) * 8];
  f32x4 att[4];
#pragma unroll
  for (int n = 0; n < 4; ++n) att[n] = ZERO4;
#pragma unroll
  for (int n = 0; n < 4; ++n) {
    const __hip_bfloat16* kl = &k_lat[((size_t)bh * 64 + n * 16 + (l & 15)) * 64];
    const short8 b0 = *(const short8*)&kl[(l >> 4) * 8];
    const short8 b1 = *(const short8*)&kl[32 + (l >> 4) * 8];
    att[n] = mfma16(a0, b0, att[n]);
    att[n] = mfma16(a1, b1, att[n]);
  }
  float p[4][4];
#pragma unroll
  for (int r = 0; r < 4; ++r) {
    const float v0 = att[0][r] * 0.125f, v1 = att[1][r] * 0.125f;
    const float v2 = att[2][r] * 0.125f, v3 = att[3][r] * 0.125f;
    float mxv = fmaxf(fmaxf(v0, v1), fmaxf(v2, v3));
#pragma unroll
    for (int o = 1; o < 16; o <<= 1) mxv = fmaxf(mxv, __shfl_xor(mxv, o, 64));
    const float e0 = __expf(v0 - mxv), e1 = __expf(v1 - mxv);
    const float e2 = __expf(v2 - mxv), e3 = __expf(v3 - mxv);
    float sum = e0 + e1 + e2 + e3;
#pragma unroll
    for (int o = 1; o < 16; o <<= 1) sum += __shfl_xor(sum, o, 64);
    const float inv = 1.f / sum;
    p[0][r] = e0 * inv; p[1][r] = e1 * inv; p[2][r] = e2 * inv; p[3][r] = e3 * inv;
  }
  // C-layout -> LDS (swizzled) -> A-layout
#pragma unroll
  for (int n = 0; n < 4; ++n)
#pragma unroll
    for (int r = 0; r < 4; ++r) {
      const int row = 4 * (l >> 4) + r;
      const int col = n * 16 + (l & 15);
      Pl[w][row][col ^ ((row & 7) << 3)] = f2bf(p[n][r]);
    }
  __syncthreads();
  const int arow = l & 15;
  const short8 pa0 = *(const short8*)&Pl[w][arow][(((l >> 4) + 0) ^ (arow & 7)) * 8];
  const short8 pa1 = *(const short8*)&Pl[w][arow][(((l >> 4) + 4) ^ (arow & 7)) * 8];
  f32x4 ov[4];
#pragma unroll
  for (int n = 0; n < 4; ++n) ov[n] = ZERO4;
#pragma unroll
  for (int n = 0; n < 4; ++n) {
    const __hip_bfloat16* vt = &v_latT[((size_t)bh * 64 + n * 16 + (l & 15)) * 64];
    const short8 b0 = *(const short8*)&vt[(l >> 4) * 8];
    const short8 b1 = *(const short8*)&vt[32 + (l >> 4) * 8];
    ov[n] = mfma16(pa0, b0, ov[n]);
    ov[n] = mfma16(pa1, b1, ov[n]);
  }
#pragma unroll
  for (int n = 0; n < 4; ++n) {
    const int d = n * 16 + (l & 15);
#pragma unroll
    for (int r = 0; r < 4; ++r) {
      const int trow = tt + w * 16 + 4 * (l >> 4) + r;
      attn[((size_t)(b * 4096 + trow) * 16 + h) * 64 + d] = __float2bfloat16(ov[n][r]);
    }
  }
}

// ---------------------------------------------------------------- launch
extern "C" void kernel_launch(void* const* d_in, const int* in_sizes, int n_in,
                              void* d_out, int out_size, void* d_ws, size_t ws_size,
                              hipStream_t stream) {
  const float* x      = (const float*)d_in[0];
  const float* Wq     = (const float*)d_in[1];
  const float* Wk     = (const float*)d_in[2];
  const float* Wv     = (const float*)d_in[3];
  const float* Wo     = (const float*)d_in[4];
  const float* latent = (const float*)d_in[5];
  const float* cosT   = (const float*)d_in[6];
  const float* sinT   = (const float*)d_in[7];
  const int*   mask   = (const int*)d_in[8];

  char* ws = (char*)d_ws;
  __hip_bfloat16* xb = (__hip_bfloat16*)ws;                                 // 33.5MB (reused as Pt)
  __hip_bfloat16* Wb = (__hip_bfloat16*)(ws + 33554432);                    // 8.4MB (4 mats)
  __hip_bfloat16* qb = (__hip_bfloat16*)(ws + 33554432 + 8388608);          // 33.5MB
  __hip_bfloat16* kb = (__hip_bfloat16*)(ws + 33554432 + 8388608 + 33554432);
  __hip_bfloat16* vb = (__hip_bfloat16*)(ws + 33554432 + 8388608 + 2*33554432); // reused as attn
  char* tail = ws + 33554432 + 8388608 + (size_t)3 * 33554432;
  float* pmax = (float*)tail;              // 32768 f
  float* psum = pmax + 32768;
  float* cmax = psum + 32768;              // 4096 f
  float* cinv = cmax + 4096;
  __hip_bfloat16* k_lat  = (__hip_bfloat16*)(cinv + 4096);  // 262144 bf16
  __hip_bfloat16* v_latT = k_lat + 262144;

  __hip_bfloat16* Pt   = xb;   // xb dead after QKV gemms
  __hip_bfloat16* attn = vb;   // vb dead after latgemm

  cvt_bf16<<<16384, 256, 0, stream>>>(x, xb, 16777216);
  cvt_bf16<<<1024, 256, 0, stream>>>(Wq, Wb + 0 * 1048576, 1048576);
  cvt_bf16<<<1024, 256, 0, stream>>>(Wk, Wb + 1 * 1048576, 1048576);
  cvt_bf16<<<1024, 256, 0, stream>>>(Wv, Wb + 2 * 1048576, 1048576);
  cvt_bf16<<<1024, 256, 0, stream>>>(Wo, Wb + 3 * 1048576, 1048576);

  dim3 gg(128, 8);
  gemm128<1><<<gg, 256, 0, stream>>>(xb, Wb + 0 * 1048576, qb, 16384, 1024, 1024);
  gemm128<1><<<gg, 256, 0, stream>>>(xb, Wb + 1 * 1048576, kb, 16384, 1024, 1024);
  gemm128<1><<<gg, 256, 0, stream>>>(xb, Wb + 2 * 1048576, vb, 16384, 1024, 1024);

  rope_inplace<<<32768, 256, 0, stream>>>((unsigned int*)qb, cosT, sinT);
  rope_inplace<<<32768, 256, 0, stream>>>((unsigned int*)kb, cosT, sinT);

  dim3 sg(64, 8);
  stage1_stats<<<sg, 256, 0, stream>>>(kb, latent, mask, pmax, psum);
  stage1_reduce<<<16, 256, 0, stream>>>(pmax, psum, cmax, cinv);
  stage1_pvals<<<1024, 256, 0, stream>>>(kb, latent, mask, cmax, cinv, Pt);
  latgemm<<<64, 256, 0, stream>>>(Pt, kb, vb, k_lat, v_latT);
  stage2_attn<<<4096, 256, 0, stream>>>(qb, k_lat, v_latT, attn);
  gemm128<0><<<gg, 256, 0, stream>>>(attn, Wb + 3 * 1048576, d_out, 16384, 1024, 1024);
}

// Round 2
// 539.501 us; speedup vs baseline: 1.1648x; 1.1648x over previous
//
#include <hip/hip_runtime.h>
#include <hip/hip_bf16.h>
#include <stdint.h>

// MLAAttention on MI355X (gfx950).
// B=4 T=4096 D=1024 H=16 M=64 Dh=64. All inputs f32 (mask int32), output f32.
// R2: latgemm re-architected (transposed K/V emitted by projection GEMMs, split-K
//     over 8 t-chunks with f32 atomics); RoPE fused into q/k GEMM epilogues.

#define DEV static __device__ __forceinline__

using short8 = __attribute__((ext_vector_type(8))) short;
using f32x4  = __attribute__((ext_vector_type(4))) float;

#define ZERO4 (f32x4){0.f, 0.f, 0.f, 0.f}

DEV float bf2f(unsigned short u) {
  union { unsigned int i; float f; } c; c.i = ((unsigned int)u) << 16; return c.f;
}
DEV unsigned short f2bf(float f) {
  __hip_bfloat16 h = __float2bfloat16(f);
  unsigned short u; __builtin_memcpy(&u, &h, 2); return u;
}
DEV f32x4 mfma16(short8 a, short8 b, f32x4 c) {
  return __builtin_amdgcn_mfma_f32_16x16x32_bf16(a, b, c, 0, 0, 0);
}
#define GLOAD_LDS16(G, L) __builtin_amdgcn_global_load_lds( \
    (const __attribute__((address_space(1))) void*)(G),     \
    (__attribute__((address_space(3))) void*)(L), 16, 0, 0)

// ---------------------------------------------------------------- convert
__global__ void cvt_bf16(const float* __restrict__ src,
                         __hip_bfloat16* __restrict__ dst, int n) {
  int i = (blockIdx.x * blockDim.x + threadIdx.x) * 4;
  if (i >= n) return;
  const float4 v = *(const float4*)(src + i);
  ushort4 o;
  o.x = f2bf(v.x); o.y = f2bf(v.y); o.z = f2bf(v.z); o.w = f2bf(v.w);
  *(ushort4*)(dst + i) = o;
}

__global__ void zero_f32(float* __restrict__ p, int n) {
  int i = (blockIdx.x * 256 + threadIdx.x) * 4;
  if (i < n) *(float4*)(p + i) = make_float4(0.f, 0.f, 0.f, 0.f);
}

// ---------------------------------------------------------------- GEMM 128x128
// C[M,N] = A[M,K] @ Bt[N,K]^T, bf16 in, f32 acc. m97 structure.
// MODE: 0 = f32 normal; 1 = bf16 normal; 2 = bf16 normal + bf16 transposed;
//       3 = bf16 transposed only.
// ROPE: apply rotary (pairs along n; t = m&4095, d = n&63) to acc before stores.
// Transposed layout: Ct[((m>>12)*16 + (n>>6))*64 + (n&63)][t = m&4095]  (bf16)
template<int MODE, int ROPE>
__global__ __launch_bounds__(256)
void gemm128(const __hip_bfloat16* __restrict__ A,
             const __hip_bfloat16* __restrict__ Bt,
             void* __restrict__ Cout, __hip_bfloat16* __restrict__ Ct,
             const float* __restrict__ cosT, const float* __restrict__ sinT,
             int M, int N, int K) {
  __shared__ __hip_bfloat16 As[128 * 64];
  __shared__ __hip_bfloat16 Bs[128 * 64];
  const int tid = threadIdx.x;
  const int w = tid >> 6, l = tid & 63;
  const int rowA0 = blockIdx.x * 128;
  const int colB0 = blockIdx.y * 128;
  const int srow = w * 8 + (l >> 3);
  const int skk  = (l & 7) * 8;
  const __hip_bfloat16* Ab = A  + (size_t)(rowA0 + srow) * K + skk;
  const __hip_bfloat16* Bb = Bt + (size_t)(colB0 + srow) * K + skk;
  f32x4 acc[4][4];
#pragma unroll
  for (int i = 0; i < 4; ++i)
#pragma unroll
    for (int j = 0; j < 4; ++j) acc[i][j] = ZERO4;
  const int wr = (w >> 1) * 64, wc = (w & 1) * 64;
  for (int k0 = 0; k0 < K; k0 += 64) {
    __syncthreads();
#pragma unroll
    for (int i = 0; i < 4; ++i) {
      GLOAD_LDS16(Ab + (size_t)(i * 32) * K + k0, &As[i * 2048 + w * 512]);
      GLOAD_LDS16(Bb + (size_t)(i * 32) * K + k0, &Bs[i * 2048 + w * 512]);
    }
    __syncthreads();
#pragma unroll
    for (int s = 0; s < 2; ++s) {
      short8 fa[4], fb[4];
#pragma unroll
      for (int i = 0; i < 4; ++i)
        fa[i] = *(const short8*)&As[(wr + i * 16 + (l & 15)) * 64 + s * 32 + (l >> 4) * 8];
#pragma unroll
      for (int j = 0; j < 4; ++j)
        fb[j] = *(const short8*)&Bs[(wc + j * 16 + (l & 15)) * 64 + s * 32 + (l >> 4) * 8];
#pragma unroll
      for (int i = 0; i < 4; ++i)
#pragma unroll
        for (int j = 0; j < 4; ++j)
          acc[i][j] = mfma16(fa[i], fb[j], acc[i][j]);
    }
  }
  const int r0 = rowA0 + wr + (l >> 4) * 4;   // global row (m) base, +i*16+r
  const int c0 = colB0 + wc + (l & 15);       // global col (n), +j*16
  if (ROPE) {
#pragma unroll
    for (int i = 0; i < 4; ++i)
#pragma unroll
      for (int j = 0; j < 4; ++j)
#pragma unroll
        for (int r = 0; r < 4; ++r) {
          const int m = r0 + i * 16 + r;
          const int n = c0 + j * 16;
          const int t = m & 4095, d = n & 63;
          const float c = cosT[t * 64 + d];
          const float s = sinT[t * 64 + d];
          const float v = acc[i][j][r];
          const float other = __shfl_xor(v, 1, 64);
          acc[i][j][r] = v * c + ((n & 1) ? other : -other) * s;
        }
  }
  if (MODE <= 2) {
#pragma unroll
    for (int i = 0; i < 4; ++i)
#pragma unroll
      for (int j = 0; j < 4; ++j)
#pragma unroll
        for (int r = 0; r < 4; ++r) {
          const size_t idx = (size_t)(r0 + i * 16 + r) * N + (c0 + j * 16);
          if (MODE == 0) ((float*)Cout)[idx] = acc[i][j][r];
          else ((__hip_bfloat16*)Cout)[idx] = __float2bfloat16(acc[i][j][r]);
        }
  }
  if (MODE >= 2) {
#pragma unroll
    for (int i = 0; i < 4; ++i)
#pragma unroll
      for (int j = 0; j < 4; ++j) {
        const int m0 = r0 + i * 16;           // 4 contiguous t per lane
        const int n  = c0 + j * 16;
        const size_t row = (size_t)(((m0 >> 12) * 16 + (n >> 6)) * 64 + (n & 63));
        ushort4 pk;
        pk.x = f2bf(acc[i][j][0]); pk.y = f2bf(acc[i][j][1]);
        pk.z = f2bf(acc[i][j][2]); pk.w = f2bf(acc[i][j][3]);
        *(ushort4*)&Ct[row * 4096 + (m0 & 4095)] = pk;
      }
  }
}

// ---------------------------------------------------------------- stage1 stats
__global__ __launch_bounds__(256)
void stage1_stats(const __hip_bfloat16* __restrict__ kmat,  // [B,T,H,64] (roped)
                  const float* __restrict__ latent,          // [H,64,64]
                  const int* __restrict__ mask,              // [B*T]
                  float* __restrict__ pmax, float* __restrict__ psum) {
  __shared__ __hip_bfloat16 kt[64][64];
  __shared__ float rmx[256], rsm[256];
  const int bh = blockIdx.x, chunk = blockIdx.y;
  const int b = bh >> 4, h = bh & 15;
  const int tid = threadIdx.x, m = tid & 63, g = tid >> 6;
  float latr[64];
#pragma unroll
  for (int d4 = 0; d4 < 16; ++d4) {
    const float4 v = *(const float4*)&latent[((size_t)(h * 64 + m)) * 64 + d4 * 4];
    latr[d4 * 4 + 0] = v.x; latr[d4 * 4 + 1] = v.y;
    latr[d4 * 4 + 2] = v.z; latr[d4 * 4 + 3] = v.w;
  }
  float mx = -3.0e38f, sm = 0.f;
  const int tbase = chunk * 512;
  for (int tt = 0; tt < 512; tt += 64) {
    __syncthreads();
    for (int i = tid; i < 512; i += 256) {
      const int r = i >> 3, o = (i & 7) * 8;
      *(uint4*)&kt[r][o] =
          *(const uint4*)&kmat[((size_t)(b * 4096 + tbase + tt + r) * 16 + h) * 64 + o];
    }
    __syncthreads();
    for (int tl = 0; tl < 16; ++tl) {
      const int t = g * 16 + tl;
      float dot = 0.f;
#pragma unroll
      for (int d8 = 0; d8 < 8; ++d8) {
        const short8 kv = *(const short8*)&kt[t][d8 * 8];
#pragma unroll
        for (int jj = 0; jj < 8; ++jj)
          dot += bf2f((unsigned short)kv[jj]) * latr[d8 * 8 + jj];
      }
      dot *= 0.125f;
      if (mask[b * 4096 + tbase + tt + t] != 0) {
        const float nmx = fmaxf(mx, dot);
        sm = sm * __expf(mx - nmx) + __expf(dot - nmx);
        mx = nmx;
      }
    }
  }
  rmx[tid] = mx; rsm[tid] = sm;
  __syncthreads();
  if (g == 0) {
#pragma unroll
    for (int gg = 1; gg < 4; ++gg) {
      const float omx = rmx[gg * 64 + m], osm = rsm[gg * 64 + m];
      const float nmx = fmaxf(mx, omx);
      sm = sm * __expf(mx - nmx) + osm * __expf(omx - nmx);
      mx = nmx;
    }
    pmax[((size_t)bh * 8 + chunk) * 64 + m] = mx;
    psum[((size_t)bh * 8 + chunk) * 64 + m] = sm;
  }
}

__global__ void stage1_reduce(const float* __restrict__ pmax,
                              const float* __restrict__ psum,
                              float* __restrict__ cmax, float* __restrict__ cinv) {
  const int i = blockIdx.x * 256 + threadIdx.x;
  if (i >= 4096) return;
  const int bh = i >> 6, m = i & 63;
  float mx = -3.0e38f;
#pragma unroll
  for (int c = 0; c < 8; ++c)
    mx = fmaxf(mx, pmax[((size_t)bh * 8 + c) * 64 + m]);
  float sm = 0.f;
#pragma unroll
  for (int c = 0; c < 8; ++c)
    sm += psum[((size_t)bh * 8 + c) * 64 + m] *
          __expf(pmax[((size_t)bh * 8 + c) * 64 + m] - mx);
  cmax[i] = mx;
  cinv[i] = 1.f / sm;
}

// P^T materialization: Pt[bh, m, t] bf16 (coalesced over t = lane)
__global__ __launch_bounds__(256)
void stage1_pvals(const __hip_bfloat16* __restrict__ kmat,
                  const float* __restrict__ latent,
                  const int* __restrict__ mask,
                  const float* __restrict__ cmax, const float* __restrict__ cinv,
                  __hip_bfloat16* __restrict__ Pt) {
  const int bh = blockIdx.x >> 4;
  const int t = (blockIdx.x & 15) * 256 + threadIdx.x;
  const int b = bh >> 4, h = bh & 15;
  float kr[64];
  {
    const __hip_bfloat16* kp = &kmat[((size_t)(b * 4096 + t) * 16 + h) * 64];
#pragma unroll
    for (int d8 = 0; d8 < 8; ++d8) {
      const short8 kv = *(const short8*)&kp[d8 * 8];
#pragma unroll
      for (int jj = 0; jj < 8; ++jj) kr[d8 * 8 + jj] = bf2f((unsigned short)kv[jj]);
    }
  }
  const bool live = (mask[b * 4096 + t] != 0);
  for (int m = 0; m < 64; ++m) {
    const float* lp = &latent[((size_t)h * 64 + m) * 64];
    float dot = 0.f;
#pragma unroll
    for (int dd = 0; dd < 64; ++dd) dot += kr[dd] * lp[dd];
    dot *= 0.125f;
    const float p = live ? __expf(dot - cmax[bh * 64 + m]) * cinv[bh * 64 + m] : 0.f;
    Pt[((size_t)bh * 64 + m) * 4096 + t] = __float2bfloat16(p);
  }
}

// ---------------------------------------------------------------- latent GEMM v2
// k_lat[m,d] = sum_t Pt[m,t]*kT[d,t];  v_latT[d,m] = sum_t vT[d,t]*Pt[m,t].
// grid (bh=64, chunk=8 of 512 t); f32 atomic partials.
__global__ __launch_bounds__(256)
void latgemm2(const __hip_bfloat16* __restrict__ Pt,
              const __hip_bfloat16* __restrict__ kT,
              const __hip_bfloat16* __restrict__ vT,
              float* __restrict__ klat_f, float* __restrict__ vlatT_f) {
  __shared__ __hip_bfloat16 Ps[64 * 64];
  __shared__ __hip_bfloat16 Ks[64 * 64];
  __shared__ __hip_bfloat16 Vs[64 * 64];
  const int bh = blockIdx.x, chunk = blockIdx.y;
  const int tid = threadIdx.x, w = tid >> 6, l = tid & 63;
  const int wr = w >> 1, wc = w & 1;
  f32x4 ak[2][2], av[2][2];
#pragma unroll
  for (int i = 0; i < 2; ++i)
#pragma unroll
    for (int j = 0; j < 2; ++j) { ak[i][j] = ZERO4; av[i][j] = ZERO4; }
  const int srow = l >> 3, scol = (l & 7) * 8;
  const size_t pbase = (size_t)bh * 64 * 4096;
  for (int st = 0; st < 8; ++st) {
    const int tb = chunk * 512 + st * 64;
    __syncthreads();
#pragma unroll
    for (int c = 0; c < 2; ++c) {
      const int rb = c * 32 + w * 8;
      const size_t go = pbase + (size_t)(rb + srow) * 4096 + tb + scol;
      GLOAD_LDS16(Pt + go, &Ps[rb * 64]);
      GLOAD_LDS16(kT + go, &Ks[rb * 64]);
      GLOAD_LDS16(vT + go, &Vs[rb * 64]);
    }
    __syncthreads();
#pragma unroll
    for (int s = 0; s < 2; ++s) {
      short8 fp[4], fk[2], fv[2];
#pragma unroll
      for (int q = 0; q < 4; ++q)
        fp[q] = *(const short8*)&Ps[(q * 16 + (l & 15)) * 64 + s * 32 + (l >> 4) * 8];
#pragma unroll
      for (int j = 0; j < 2; ++j)
        fk[j] = *(const short8*)&Ks[(wc * 32 + j * 16 + (l & 15)) * 64 + s * 32 + (l >> 4) * 8];
#pragma unroll
      for (int i = 0; i < 2; ++i)
        fv[i] = *(const short8*)&Vs[(wr * 32 + i * 16 + (l & 15)) * 64 + s * 32 + (l >> 4) * 8];
#pragma unroll
      for (int i = 0; i < 2; ++i)
#pragma unroll
        for (int j = 0; j < 2; ++j) {
          ak[i][j] = mfma16(fp[wr * 2 + i], fk[j], ak[i][j]);
          av[i][j] = mfma16(fv[i], fp[wc * 2 + j], av[i][j]);
        }
    }
  }
  const size_t base = (size_t)bh * 4096;
#pragma unroll
  for (int i = 0; i < 2; ++i)
#pragma unroll
    for (int j = 0; j < 2; ++j)
#pragma unroll
      for (int r = 0; r < 4; ++r) {
        const int rk = wr * 32 + i * 16 + (l >> 4) * 4 + r;   // m (k) / d (v)
        const int ck = wc * 32 + j * 16 + (l & 15);           // d (k) / m (v)
        atomicAdd(&klat_f[base + (size_t)rk * 64 + ck], ak[i][j][r]);
        atomicAdd(&vlatT_f[base + (size_t)rk * 64 + ck], av[i][j][r]);
      }
}

// ---------------------------------------------------------------- stage2 fused
__global__ __launch_bounds__(256)
void stage2_attn(const __hip_bfloat16* __restrict__ q,
                 const __hip_bfloat16* __restrict__ k_lat,
                 const __hip_bfloat16* __restrict__ v_latT,
                 __hip_bfloat16* __restrict__ attn) {
  __shared__ unsigned short Pl[4][16][64];
  const int bid = blockIdx.x;
  const int bh = bid >> 6, tt = (bid & 63) * 64;
  const int b = bh >> 4, h = bh & 15;
  const int tid = threadIdx.x, w = tid >> 6, l = tid & 63;
  const size_t qoff = ((size_t)(b * 4096 + tt + w * 16 + (l & 15)) * 16 + h) * 64;
  const short8 a0 = *(const short8*)&q[qoff + (l >> 4) * 8];
  const short8 a1 = *(const short8*)&q[qoff + 32 + (l >> 4) * 8];
  f32x4 att[4];
#pragma unroll
  for (int n = 0; n < 4; ++n) att[n] = ZERO4;
#pragma unroll
  for (int n = 0; n < 4; ++n) {
    const __hip_bfloat16* kl = &k_lat[((size_t)bh * 64 + n * 16 + (l & 15)) * 64];
    const short8 b0 = *(const short8*)&kl[(l >> 4) * 8];
    const short8 b1 = *(const short8*)&kl[32 + (l >> 4) * 8];
    att[n] = mfma16(a0, b0, att[n]);
    att[n] = mfma16(a1, b1, att[n]);
  }
  float p[4][4];
#pragma unroll
  for (int r = 0; r < 4; ++r) {
    const float v0 = att[0][r] * 0.125f, v1 = att[1][r] * 0.125f;
    const float v2 = att[2][r] * 0.125f, v3 = att[3][r] * 0.125f;
    float mxv = fmaxf(fmaxf(v0, v1), fmaxf(v2, v3));
#pragma unroll
    for (int o = 1; o < 16; o <<= 1) mxv = fmaxf(mxv, __shfl_xor(mxv, o, 64));
    const float e0 = __expf(v0 - mxv), e1 = __expf(v1 - mxv);
    const float e2 = __expf(v2 - mxv), e3 = __expf(v3 - mxv);
    float sum = e0 + e1 + e2 + e3;
#pragma unroll
    for (int o = 1; o < 16; o <<= 1) sum += __shfl_xor(sum, o, 64);
    const float inv = 1.f / sum;
    p[0][r] = e0 * inv; p[1][r] = e1 * inv; p[2][r] = e2 * inv; p[3][r] = e3 * inv;
  }
#pragma unroll
  for (int n = 0; n < 4; ++n)
#pragma unroll
    for (int r = 0; r < 4; ++r) {
      const int row = 4 * (l >> 4) + r;
      const int col = n * 16 + (l & 15);
      Pl[w][row][col ^ ((row & 7) << 3)] = f2bf(p[n][r]);
    }
  __syncthreads();
  const int arow = l & 15;
  const short8 pa0 = *(const short8*)&Pl[w][arow][(((l >> 4) + 0) ^ (arow & 7)) * 8];
  const short8 pa1 = *(const short8*)&Pl[w][arow][(((l >> 4) + 4) ^ (arow & 7)) * 8];
  f32x4 ov[4];
#pragma unroll
  for (int n = 0; n < 4; ++n) ov[n] = ZERO4;
#pragma unroll
  for (int n = 0; n < 4; ++n) {
    const __hip_bfloat16* vt = &v_latT[((size_t)bh * 64 + n * 16 + (l & 15)) * 64];
    const short8 b0 = *(const short8*)&vt[(l >> 4) * 8];
    const short8 b1 = *(const short8*)&vt[32 + (l >> 4) * 8];
    ov[n] = mfma16(pa0, b0, ov[n]);
    ov[n] = mfma16(pa1, b1, ov[n]);
  }
#pragma unroll
  for (int n = 0; n < 4; ++n) {
    const int d = n * 16 + (l & 15);
#pragma unroll
    for (int r = 0; r < 4; ++r) {
      const int trow = tt + w * 16 + 4 * (l >> 4) + r;
      attn[((size_t)(b * 4096 + trow) * 16 + h) * 64 + d] = __float2bfloat16(ov[n][r]);
    }
  }
}

// ---------------------------------------------------------------- launch
extern "C" void kernel_launch(void* const* d_in, const int* in_sizes, int n_in,
                              void* d_out, int out_size, void* d_ws, size_t ws_size,
                              hipStream_t stream) {
  const float* x      = (const float*)d_in[0];
  const float* Wq     = (const float*)d_in[1];
  const float* Wk     = (const float*)d_in[2];
  const float* Wv     = (const float*)d_in[3];
  const float* Wo     = (const float*)d_in[4];
  const float* latent = (const float*)d_in[5];
  const float* cosT   = (const float*)d_in[6];
  const float* sinT   = (const float*)d_in[7];
  const int*   mask   = (const int*)d_in[8];

  char* ws = (char*)d_ws;
  __hip_bfloat16* xb = (__hip_bfloat16*)ws;                        // 33.5MB (reused as Pt)
  __hip_bfloat16* Wb = (__hip_bfloat16*)(ws + 33554432);           // 8.4MB
  __hip_bfloat16* qb = (__hip_bfloat16*)(ws + 41943040);           // 33.5MB (reused as attn, in-place)
  __hip_bfloat16* kb = (__hip_bfloat16*)(ws + 75497472);           // 33.5MB
  __hip_bfloat16* kT = (__hip_bfloat16*)(ws + 109051904);          // 33.5MB [bh*64+d][t]
  __hip_bfloat16* vT = (__hip_bfloat16*)(ws + 142606336);          // 33.5MB
  char* tail = ws + 176160768;
  float* pmax = (float*)tail;                       // 32768 f
  float* psum = pmax + 32768;
  float* cmax = psum + 32768;                       // 4096 f
  float* cinv = cmax + 4096;
  float* klat_f  = cinv + 4096;                     // 262144 f
  float* vlatT_f = klat_f + 262144;                 // 262144 f
  __hip_bfloat16* k_lat  = (__hip_bfloat16*)(vlatT_f + 262144);   // 262144 bf16
  __hip_bfloat16* v_latT = k_lat + 262144;

  __hip_bfloat16* Pt   = xb;
  __hip_bfloat16* attn = qb;

  cvt_bf16<<<16384, 256, 0, stream>>>(x, xb, 16777216);
  cvt_bf16<<<1024, 256, 0, stream>>>(Wq, Wb + 0 * 1048576, 1048576);
  cvt_bf16<<<1024, 256, 0, stream>>>(Wk, Wb + 1 * 1048576, 1048576);
  cvt_bf16<<<1024, 256, 0, stream>>>(Wv, Wb + 2 * 1048576, 1048576);
  cvt_bf16<<<1024, 256, 0, stream>>>(Wo, Wb + 3 * 1048576, 1048576);
  zero_f32<<<512, 256, 0, stream>>>(klat_f, 524288);   // klat_f + vlatT_f (adjacent)

  dim3 gg(128, 8);
  gemm128<1, 1><<<gg, 256, 0, stream>>>(xb, Wb + 0 * 1048576, qb, nullptr, cosT, sinT, 16384, 1024, 1024);
  gemm128<2, 1><<<gg, 256, 0, stream>>>(xb, Wb + 1 * 1048576, kb, kT, cosT, sinT, 16384, 1024, 1024);
  gemm128<3, 0><<<gg, 256, 0, stream>>>(xb, Wb + 2 * 1048576, nullptr, vT, nullptr, nullptr, 16384, 1024, 1024);

  dim3 sg(64, 8);
  stage1_stats<<<sg, 256, 0, stream>>>(kb, latent, mask, pmax, psum);
  stage1_reduce<<<16, 256, 0, stream>>>(pmax, psum, cmax, cinv);
  stage1_pvals<<<1024, 256, 0, stream>>>(kb, latent, mask, cmax, cinv, Pt);

  dim3 lg(64, 8);
  latgemm2<<<lg, 256, 0, stream>>>(Pt, kT, vT, klat_f, vlatT_f);
  cvt_bf16<<<256, 256, 0, stream>>>(klat_f, k_lat, 262144);
  cvt_bf16<<<256, 256, 0, stream>>>(vlatT_f, v_latT, 262144);

  stage2_attn<<<4096, 256, 0, stream>>>(qb, k_lat, v_latT, attn);
  gemm128<0, 0><<<gg, 256, 0, stream>>>(attn, Wb + 3 * 1048576, d_out, nullptr, nullptr, nullptr, 16384, 1024, 1024);
}